// Round 1
// 251.589 us; speedup vs baseline: 1.0730x; 1.0730x over previous
//
#include <hip/hip_runtime.h>
#include <hip/hip_bf16.h>
#include <hip/hip_fp16.h>

#define N_NODES 50000
#define N_EDGES 640000
#define N_GRAPHS 500
#define D 128
#define CAP 64   // neighbor slots per node; P(Poisson(12.8) > 64) ~ 1e-30

// ---- two-level CSR build geometry ----
#define EB 250        // pass-1 edge blocks (2560 edges each, exact: 250*2560 = 640000)
#define EPB 2560      // edges per pass-1 block (10 per thread)
#define NBUCK 196     // coarse buckets, dst >> 8 (49999>>8 = 195)
#define BCAP 3840     // bucket capacity; mean 3277, sd 57 -> +9.8 sigma

#define PREP_X_BLOCKS (N_NODES * D / 8 / 256) // 3125 (exact)
#define PREP_W_BLOCKS (6 * D * D / 256)       // 384 (exact)

typedef _Float16 h8_t __attribute__((ext_vector_type(8)));   // 8 fp16 = 4 VGPRs
typedef __attribute__((ext_vector_type(4))) float f4_t;

// ---------------------------------------------------------------------------
// prep pass 1:
//  (a) edge blocks: coarse-bin edges into 196 dst-range buckets.
//      LDS histogram -> ONE global returning atomic per (block,bucket)
//      (49K fabric RMWs total vs 640K in the flat scheme) -> dense packed
//      (dst<<16|src) segment writes. Replaces the 42us flat atomic fill.
//  (b) x fp32->fp16, (c) W (L,K,N) fp32 -> fp16 transposed (L,N,K).
// ---------------------------------------------------------------------------
__global__ __launch_bounds__(256) void gin_prep1_kernel(
    const float* __restrict__ x, _Float16* __restrict__ xh,
    const int* __restrict__ src, const int* __restrict__ dst,
    unsigned* __restrict__ bucketed, int* __restrict__ bcur,
    const float* __restrict__ W1, const float* __restrict__ W2,
    _Float16* __restrict__ Wt1, _Float16* __restrict__ Wt2)
{
    const int b = blockIdx.x, t = threadIdx.x;
    if (b < EB) {
        __shared__ int hist[NBUCK], gbase[NBUCK], cur[NBUCK];
        if (t < NBUCK) { hist[t] = 0; cur[t] = 0; }
        __syncthreads();
        const int e0 = b * EPB;
        int dv[10], sv[10];
        #pragma unroll
        for (int j = 0; j < 10; ++j) {
            int e = e0 + j * 256 + t;
            dv[j] = dst[e];
            sv[j] = src[e];
        }
        #pragma unroll
        for (int j = 0; j < 10; ++j)
            atomicAdd(&hist[dv[j] >> 8], 1);
        __syncthreads();
        if (t < NBUCK) gbase[t] = atomicAdd(&bcur[t], hist[t]);   // 196/block fabric RMWs
        __syncthreads();
        #pragma unroll
        for (int j = 0; j < 10; ++j) {
            int bk = dv[j] >> 8;
            int r = atomicAdd(&cur[bk], 1);                       // LDS, cheap
            int pos = gbase[bk] + r;
            if (pos < BCAP)
                bucketed[bk * BCAP + pos] = ((unsigned)dv[j] << 16) | (unsigned)sv[j];
        }
    } else if (b < EB + PREP_X_BLOCKS) {
        int i = (b - EB) * 256 + t;                // h8-unit index
        const float4* p = (const float4*)x;
        float4 v0 = p[2 * i], v1 = p[2 * i + 1];
        h8_t o;
        o[0] = (_Float16)v0.x; o[1] = (_Float16)v0.y;
        o[2] = (_Float16)v0.z; o[3] = (_Float16)v0.w;
        o[4] = (_Float16)v1.x; o[5] = (_Float16)v1.y;
        o[6] = (_Float16)v1.z; o[7] = (_Float16)v1.w;
        ((h8_t*)xh)[i] = o;
    } else {
        int idx = (b - EB - PREP_X_BLOCKS) * 256 + t;
        int m = idx >> 14;
        int r = idx & 16383;
        int n = r >> 7, k = r & 127;
        const float* srcw = (m < 3) ? (W1 + ((long)m << 14)) : (W2 + ((long)(m - 3) << 14));
        _Float16* dstw = (m < 3) ? (Wt1 + ((long)m << 14)) : (Wt2 + ((long)(m - 3) << 14));
        dstw[(n << 7) | k] = (_Float16)srcw[(k << 7) | n];   // Wt[n][k] = W[k][n]
    }
}

// ---------------------------------------------------------------------------
// prep pass 2: one block per bucket. LDS per-node counters assign slots;
// slot writes land in a single-XCD, L2-resident 32KB region (ushort src ids).
// cnt[] written densely -> no global memset of cnt needed.
// Slot ORDER varies run-to-run; sums are exact in f64 -> bit-identical output.
// ---------------------------------------------------------------------------
__global__ __launch_bounds__(512) void gin_prep2_kernel(
    const unsigned* __restrict__ bucketed, const int* __restrict__ bcur,
    unsigned short* __restrict__ slots, int* __restrict__ cnt)
{
    __shared__ int lcnt[256];
    const int b = blockIdx.x, t = threadIdx.x;
    if (t < 256) lcnt[t] = 0;
    __syncthreads();
    int n = bcur[b];
    if (n > BCAP) n = BCAP;
    const unsigned* bp = bucketed + b * BCAP;
    for (int i = t; i < n; i += 512) {
        unsigned p = bp[i];
        int d = (int)(p >> 16);
        int sl = atomicAdd(&lcnt[d & 255], 1);                 // LDS, cheap
        if (sl < CAP) slots[((long)d << 6) + sl] = (unsigned short)(p & 0xffffu);
    }
    __syncthreads();
    if (t < 256) {
        int node = (b << 8) + t;
        if (node < N_NODES) cnt[node] = lcnt[t] < CAP ? lcnt[t] : CAP;
    }
}

// ---------------------------------------------------------------------------
// FUSED LAYER (r12 best-known structure, unchanged except ushort slots):
// out = relu(BN(relu((x_self + sum_n x) @ W1 + b1) @ W2 + b2))
// Block = 512 thr (8 waves) owns 32 nodes; grid 1563.
//  phase G: wave-per-node, 4 passes; binned slots (uniform base -> s_loads);
//   single clamped 16-window -> ONE vmcnt drain for ~85% of nodes; residual
//   loop for deg>16. TWO independent f64 accumulator pairs. All sums EXACT
//   (fp16 multiples of 2^-24, |v|<2^6, deg<2^6) -> bit-identical for ANY
//   slot order (binning varies per call).
//   Measured wall: ~1.85 TB/s beyond-L2 on random 256B rows across 8
//   structural variants (r7-r14) — memory-system bound.
//  slots are ushort now: window = 8 dwords (s_load_dwordx8), halves slot fetch.
// in/out must differ (caller ping-pongs).
// ---------------------------------------------------------------------------
constexpr int ASTR = 136;   // fp16 elems/row in LDS: +8 pad

__device__ __forceinline__ float2 unpack_h2(unsigned v) {
    __half2 h = __builtin_bit_cast(__half2, v);
    return __half22float2(h);
}

__global__ __launch_bounds__(512, 4) void gin_layer_kernel(
    const _Float16* __restrict__ x,
    const int* __restrict__ cnt, const unsigned short* __restrict__ slots,
    const _Float16* __restrict__ Wt1, const float* __restrict__ b1,
    const _Float16* __restrict__ Wt2, const float* __restrict__ b2,
    const float* __restrict__ bn_scale, const float* __restrict__ bn_bias,
    const float* __restrict__ bn_mean, const float* __restrict__ bn_var,
    _Float16* __restrict__ out, int N)
{
    __shared__ __align__(16) _Float16 a_s[32 * ASTR];
    __shared__ float ep_a[D], ep_b[D], b1_s[D];

    const int tid = threadIdx.x;
    if (tid < D) {
        float s = bn_scale[tid] * rsqrtf(bn_var[tid] + 1e-5f);
        ep_a[tid] = s;
        ep_b[tid] = (b2[tid] - bn_mean[tid]) * s + bn_bias[tid];
        b1_s[tid] = b1[tid];
    }

    const int row0 = blockIdx.x * 32;
    const int lane = tid & 63;
    const int wave_u = __builtin_amdgcn_readfirstlane(tid >> 6);   // 0..7, SGPR
    const unsigned* __restrict__ xw = (const unsigned*)x;          // dword = 2 fp16

    // ---- phase G: wave-per-node, single-drain clamped gather ----
    #pragma unroll 1
    for (int pass = 0; pass < 4; ++pass) {
        const int nl = pass * 8 + wave_u;          // 0..31, uniform
        const int node = row0 + nl;
        const bool live = (node < N);
        const int cnt_n = live ? __builtin_amdgcn_readfirstlane(cnt[node]) : 0;
        const unsigned* cw = (const unsigned*)(slots + ((long)node << 6)); // uniform base

        double a0 = 0.0, a1 = 0.0, c0 = 0.0, c1 = 0.0;
        if (live) {
            float2 f = unpack_h2(xw[(long)node * 64 + lane]);      // self
            a0 = (double)f.x; a1 = (double)f.y;

            // fixed 16-window: clamped indices for i>=cnt, masked adds
            unsigned wv[8];
            #pragma unroll
            for (int i = 0; i < 8; ++i) wv[i] = cw[i];             // s_load_dwordx8
            int idx[16];
            #pragma unroll
            for (int i = 0; i < 8; ++i) {
                idx[2 * i]     = (int)(wv[i] & 0xffffu);
                idx[2 * i + 1] = (int)(wv[i] >> 16);
            }
            unsigned v[16];
            #pragma unroll
            for (int i = 0; i < 16; ++i) {
                int j = (i < cnt_n) ? idx[i] : 0;                  // scalar select
                v[i] = xw[(long)j * 64 + lane];                    // coalesced 256B
            }
            #pragma unroll
            for (int i = 0; i < 16; i += 2) {                      // 2-way f64 ILP
                unsigned m0 = (i < cnt_n) ? v[i] : 0u;
                unsigned m1 = (i + 1 < cnt_n) ? v[i + 1] : 0u;
                float2 g0 = unpack_h2(m0);
                float2 g1 = unpack_h2(m1);
                a0 += (double)g0.x; a1 += (double)g0.y;
                c0 += (double)g1.x; c1 += (double)g1.y;
            }
            // residual (deg > 16, ~15% of nodes)
            #pragma unroll 1
            for (int k = 16; k < cnt_n; k += 8) {
                unsigned wr[4];
                #pragma unroll
                for (int i = 0; i < 4; ++i) wr[i] = cw[(k >> 1) + i];
                unsigned vv[8];
                #pragma unroll
                for (int i = 0; i < 8; ++i) {
                    int kk = k + i;
                    int j = (kk < cnt_n) ? (int)((wr[i >> 1] >> ((i & 1) * 16)) & 0xffffu) : 0;
                    vv[i] = xw[(long)j * 64 + lane];
                }
                #pragma unroll
                for (int i = 0; i < 8; i += 2) {
                    unsigned m0 = (k + i < cnt_n) ? vv[i] : 0u;
                    unsigned m1 = (k + i + 1 < cnt_n) ? vv[i + 1] : 0u;
                    float2 g0 = unpack_h2(m0);
                    float2 g1 = unpack_h2(m1);
                    a0 += (double)g0.x; a1 += (double)g0.y;
                    c0 += (double)g1.x; c1 += (double)g1.y;
                }
            }
        }
        // merge (exact: every partial sum representable)
        _Float16 h0 = (_Float16)(float)(a0 + c0);
        _Float16 h1 = (_Float16)(float)(a1 + c1);
        unsigned pk = (unsigned)__builtin_bit_cast(unsigned short, h0) |
                      ((unsigned)__builtin_bit_cast(unsigned short, h1) << 16);
        *(unsigned*)(a_s + nl * ASTR + lane * 2) = pk;             // conflict-free
    }
    __syncthreads();

    // ---- stage 1: a_s @ W1 ----  (wave w -> col tile [16w,16w+16), rows 0..31)
    const int m16 = lane & 15;
    const int kq  = lane >> 4;
    const int coln = wave_u * 16 + m16;

    f4_t a1m[2] = {(f4_t){0.f, 0.f, 0.f, 0.f}, (f4_t){0.f, 0.f, 0.f, 0.f}};
    #pragma unroll
    for (int kc = 0; kc < 4; ++kc) {
        const int k0 = kc * 32 + kq * 8;
        h8_t af0 = *(const h8_t*)(a_s + m16 * ASTR + k0);
        h8_t af1 = *(const h8_t*)(a_s + (16 + m16) * ASTR + k0);
        h8_t bf  = *(const h8_t*)(Wt1 + (long)coln * D + k0);
        a1m[0] = __builtin_amdgcn_mfma_f32_16x16x32_f16(af0, bf, a1m[0], 0, 0, 0);
        a1m[1] = __builtin_amdgcn_mfma_f32_16x16x32_f16(af1, bf, a1m[1], 0, 0, 0);
    }
    __syncthreads();   // all a_s reads done -> safe to overwrite

    // h = relu(a1m + b1) back into a_s  (C/D: col=m16, row=kq*4+g)
    {
        const float bb = b1_s[coln];
        #pragma unroll
        for (int r = 0; r < 2; ++r)
            #pragma unroll
            for (int g = 0; g < 4; ++g) {
                float vv = fmaxf(a1m[r][g] + bb, 0.f);
                a_s[(r * 16 + kq * 4 + g) * ASTR + coln] = (_Float16)vv;
            }
    }
    __syncthreads();

    // ---- stage 2: out = relu(BN(a_s @ W2 + b2)) ----
    f4_t a2m[2] = {(f4_t){0.f, 0.f, 0.f, 0.f}, (f4_t){0.f, 0.f, 0.f, 0.f}};
    #pragma unroll
    for (int kc = 0; kc < 4; ++kc) {
        const int k0 = kc * 32 + kq * 8;
        h8_t af0 = *(const h8_t*)(a_s + m16 * ASTR + k0);
        h8_t af1 = *(const h8_t*)(a_s + (16 + m16) * ASTR + k0);
        h8_t bf  = *(const h8_t*)(Wt2 + (long)coln * D + k0);
        a2m[0] = __builtin_amdgcn_mfma_f32_16x16x32_f16(af0, bf, a2m[0], 0, 0, 0);
        a2m[1] = __builtin_amdgcn_mfma_f32_16x16x32_f16(af1, bf, a2m[1], 0, 0, 0);
    }
    {
        const float ea = ep_a[coln], eb = ep_b[coln];
        #pragma unroll
        for (int r = 0; r < 2; ++r) {
            const int rb = row0 + r * 16 + kq * 4;
            #pragma unroll
            for (int g = 0; g < 4; ++g) {
                const int grow = rb + g;
                if (grow < N) {
                    float vv = fmaxf(fmaf(a2m[r][g], ea, eb), 0.f);
                    out[(long)grow * D + coln] = (_Float16)vv;
                }
            }
        }
    }
}

// ---------------------------------------------------------------------------
// fused pool+head: one block (128 thr) per graph. batch sorted -> binary
// search; fixed-order fp32 sum -> deterministic.
// ---------------------------------------------------------------------------
__global__ __launch_bounds__(128) void gin_poolhead_kernel(
    const _Float16* __restrict__ x, const int* __restrict__ batch,
    const float* __restrict__ Wh1, const float* __restrict__ bh1,
    const float* __restrict__ Wh2, const float* __restrict__ bh2,
    float* __restrict__ out, int N)
{
    const int gid = blockIdx.x;
    const int t = threadIdx.x;
    __shared__ float gs[D];
    __shared__ float hid[64];

    int lo = 0, hi = N;
    while (lo < hi) { int m = (lo + hi) >> 1; if (batch[m] < gid) lo = m + 1; else hi = m; }
    int s = lo;
    hi = N;
    while (lo < hi) { int m = (lo + hi) >> 1; if (batch[m] < gid + 1) lo = m + 1; else hi = m; }
    int e = lo;
    float a0 = 0.f, a1 = 0.f, a2 = 0.f, a3 = 0.f;
    int i = s;
    for (; i + 4 <= e; i += 4) {
        a0 += (float)x[(long)i * D + t];
        a1 += (float)x[(long)(i + 1) * D + t];
        a2 += (float)x[(long)(i + 2) * D + t];
        a3 += (float)x[(long)(i + 3) * D + t];
    }
    for (; i < e; ++i) a0 += (float)x[(long)i * D + t];
    gs[t] = (a0 + a1) + (a2 + a3);
    __syncthreads();

    if (t < 64) {
        float acc = bh1[t];
        #pragma unroll 4
        for (int k = 0; k < D; ++k) acc = fmaf(gs[k], Wh1[k * 64 + t], acc);
        hid[t] = fmaxf(acc, 0.f);
    }
    __syncthreads();
    if (t < 12) {
        float acc2 = bh2[t];
        #pragma unroll 4
        for (int j = 0; j < 64; ++j) acc2 = fmaf(hid[j], Wh2[j * 12 + t], acc2);
        out[gid * 12 + t] = 1.f / (1.f + __expf(-acc2));
    }
}

// ---------------------------------------------------------------------------
extern "C" void kernel_launch(void* const* d_in, const int* in_sizes, int n_in,
                              void* d_out, int out_size, void* d_ws, size_t ws_size,
                              hipStream_t stream) {
    const float* x    = (const float*)d_in[0];
    const int*   edge = (const int*)d_in[1];
    const int*   batch= (const int*)d_in[2];
    const float* W1   = (const float*)d_in[3];
    const float* b1   = (const float*)d_in[4];
    const float* W2   = (const float*)d_in[5];
    const float* b2   = (const float*)d_in[6];
    const float* bns  = (const float*)d_in[7];
    const float* bnb  = (const float*)d_in[8];
    const float* bnm  = (const float*)d_in[9];
    const float* bnv  = (const float*)d_in[10];
    const float* Wh1  = (const float*)d_in[11];
    const float* bh1  = (const float*)d_in[12];
    const float* Wh2  = (const float*)d_in[13];
    const float* bh2  = (const float*)d_in[14];
    float* outp = (float*)d_out;

    const int* esrc = edge;
    const int* edst = edge + N_EDGES;

    char* ws = (char*)d_ws;
    size_t off = 0;
    auto alloc = [&](size_t bytes) -> void* {
        void* p = ws + off;
        off += (bytes + 255) & ~(size_t)255;
        return p;
    };
    _Float16* x_h   = (_Float16*)alloc((size_t)N_NODES * D * 2);
    _Float16* bufA  = (_Float16*)alloc((size_t)N_NODES * D * 2);
    _Float16* bufB  = (_Float16*)alloc((size_t)N_NODES * D * 2);
    _Float16* Wt1   = (_Float16*)alloc((size_t)3 * D * D * 2);
    _Float16* Wt2   = (_Float16*)alloc((size_t)3 * D * D * 2);
    unsigned short* slots = (unsigned short*)alloc((size_t)N_NODES * CAP * 2 + 256); // +pad
    int*      cnt      = (int*)alloc((size_t)N_NODES * 4);
    unsigned* bucketed = (unsigned*)alloc((size_t)NBUCK * BCAP * 4);
    int*      bcur     = (int*)alloc(256 * 4);
    if (off > ws_size) return;

    hipMemsetAsync(bcur, 0, NBUCK * 4, stream);   // 784 B, replaces 200 KB cnt memset

    gin_prep1_kernel<<<EB + PREP_X_BLOCKS + PREP_W_BLOCKS, 256, 0, stream>>>(
        x, x_h, esrc, edst, bucketed, bcur, W1, W2, Wt1, Wt2);

    gin_prep2_kernel<<<NBUCK, 512, 0, stream>>>(bucketed, bcur, slots, cnt);

    const int GLAYER = (N_NODES + 31) / 32;   // 1563 blocks, 32 nodes each

    // ping-pong: layer reads one buffer, writes the other
    const _Float16* lin[3]  = {x_h,  bufA, bufB};
    _Float16*       lout[3] = {bufA, bufB, bufA};
    for (int l = 0; l < 3; ++l) {
        gin_layer_kernel<<<GLAYER, 512, 0, stream>>>(
            lin[l], cnt, slots,
            Wt1 + (size_t)l * D * D, b1 + l * D,
            Wt2 + (size_t)l * D * D, b2 + l * D,
            bns + l * D, bnb + l * D, bnm + l * D, bnv + l * D,
            lout[l], N_NODES);
    }

    gin_poolhead_kernel<<<N_GRAPHS, 128, 0, stream>>>(bufA, batch, Wh1, bh1, Wh2, bh2, outp, N_NODES);
}